// Round 1
// baseline (446.253 us; speedup 1.0000x reference)
//
#include <hip/hip_runtime.h>
#include <stdint.h>

// DP_Attention: B=8, S=4096, D=K=1024, fp32.
//   fq = q@Wq+bq (split-K matvec) ; g[b]=Wk@fq[b], cb[b]=fq.bk
//   attn = sigmoid((g.k_s+cb)/32)            (stream k, 134 MB; dual-store: d_out + ws)
//   vb = bf16(v)                             (per-HALF: 32 MiB buffer, keeps ws <= 36 MiB)
//   norm2[b,s] = ||v_s@Wv + bv||^2           (m97-style MFMA GEMM, BK=64,
//                                             global_load_lds + src-side XOR swizzle)
//   y[b] = sum_s coef_s v_s (from vb), csum  (stream vb, L3-hot)
//   seed = y@Wv + csum*bv + 0.1*noise        (split-K + threefry partitionable)
//
// NOTE on ws layout: previous version placed vb at [4MiB, 68MiB). The post-timing
// divergence (seed wrong by 0.449 on calls 2+, attn fine) is consistent with vb's
// tail writes landing past d_ws and corrupting an adjacent input buffer (v/Wv).
// This version halves vb (process b in two groups of 4) -> ws high-water 36 MiB,
// and never reads intermediates from d_out.

#define Bn 8
#define Sn 4096
#define Dn 1024
#define Kn 1024

typedef unsigned short u16;
typedef __attribute__((ext_vector_type(4))) unsigned short u16x4;
typedef __attribute__((ext_vector_type(8))) unsigned short u16x8;
typedef __attribute__((ext_vector_type(8))) __bf16 bf16x8;
typedef __attribute__((ext_vector_type(4))) float f32x4;

__device__ __forceinline__ u16 f2bf(float f) {
  uint32_t x = __float_as_uint(f);
  x += 0x7FFFu + ((x >> 16) & 1u);   // RNE
  return (u16)(x >> 16);
}
__device__ __forceinline__ float bf2f(u16 h) {
  return __uint_as_float(((uint32_t)h) << 16);
}

// ---------------- JAX threefry2x32 (key=(0,1234)), partitionable ----------------
__device__ __forceinline__ uint32_t rotl32(uint32_t x, int d) {
  return (x << d) | (x >> (32 - d));
}
__device__ void threefry2x32(uint32_t k0, uint32_t k1, uint32_t x0, uint32_t x1,
                             uint32_t* o0, uint32_t* o1) {
  uint32_t ks0 = k0, ks1 = k1, ks2 = k0 ^ k1 ^ 0x1BD11BDAu;
  x0 += ks0; x1 += ks1;
#define TF_R4(a,b,c,d) \
  x0 += x1; x1 = rotl32(x1,a); x1 ^= x0; \
  x0 += x1; x1 = rotl32(x1,b); x1 ^= x0; \
  x0 += x1; x1 = rotl32(x1,c); x1 ^= x0; \
  x0 += x1; x1 = rotl32(x1,d); x1 ^= x0;
  TF_R4(13,15,26,6);  x0 += ks1; x1 += ks2 + 1u;
  TF_R4(17,29,16,24); x0 += ks2; x1 += ks0 + 2u;
  TF_R4(13,15,26,6);  x0 += ks0; x1 += ks1 + 3u;
  TF_R4(17,29,16,24); x0 += ks1; x1 += ks2 + 4u;
  TF_R4(13,15,26,6);  x0 += ks2; x1 += ks0 + 5u;
#undef TF_R4
  *o0 = x0; *o1 = x1;
}

__device__ float erfinv_f(float x) {
  float w = -log1pf(-x * x);
  float p;
  if (w < 5.0f) {
    w -= 2.5f;
    p = 2.81022636e-08f;
    p = fmaf(p, w, 3.43273939e-07f);
    p = fmaf(p, w, -3.5233877e-06f);
    p = fmaf(p, w, -4.39150654e-06f);
    p = fmaf(p, w, 0.00021858087f);
    p = fmaf(p, w, -0.00125372503f);
    p = fmaf(p, w, -0.00417768164f);
    p = fmaf(p, w, 0.246640727f);
    p = fmaf(p, w, 1.50140941f);
  } else {
    w = sqrtf(w) - 3.0f;
    p = -0.000200214257f;
    p = fmaf(p, w, 0.000100950558f);
    p = fmaf(p, w, 0.00134934322f);
    p = fmaf(p, w, -0.00367342844f);
    p = fmaf(p, w, 0.00573950773f);
    p = fmaf(p, w, -0.0076224613f);
    p = fmaf(p, w, 0.00943887047f);
    p = fmaf(p, w, 1.00167406f);
    p = fmaf(p, w, 2.83297682f);
  }
  return p * x;
}

// ---------------- fq = q@Wq + bq, split-K (256 blocks) ----------------
__global__ void k_fq(const float* __restrict__ q, const float* __restrict__ wq,
                     const float* __restrict__ bq, float* __restrict__ fq) {
  int blk = blockIdx.x;               // b(8) x jc(4) x dc(8)
  int b = blk >> 5, jc = (blk >> 3) & 3, dc = blk & 7;
  int j = jc * 256 + threadIdx.x;
  const float* qb = q + b * Dn;
  float acc = 0.f;
  int d0 = dc * 128;
  for (int d = d0; d < d0 + 128; ++d)
    acc = fmaf(qb[d], wq[(size_t)d * Kn + j], acc);
  if (dc == 0) acc += bq[j];
  atomicAdd(&fq[b * Kn + j], acc);
}

__global__ void k_g(const float* __restrict__ wk, const float* __restrict__ fq,
                    float* __restrict__ g) {
  int wid = (blockIdx.x * 256 + threadIdx.x) >> 6;   // 8192 waves
  int lane = threadIdx.x & 63;
  int b = wid >> 10, d = wid & 1023;
  const float* row = wk + (size_t)d * Kn;
  const float* f = fq + b * Kn;
  float acc = 0.f;
  for (int j = lane; j < Kn; j += 64) acc = fmaf(row[j], f[j], acc);
  for (int m = 32; m; m >>= 1) acc += __shfl_xor(acc, m, 64);
  if (lane == 0) g[b * Dn + d] = acc;
}

__global__ void k_cb(const float* __restrict__ fq, const float* __restrict__ bk,
                     float* __restrict__ cb) {
  int b = threadIdx.x >> 6;
  int lane = threadIdx.x & 63;
  float acc = 0.f;
  for (int j = lane; j < Kn; j += 64) acc = fmaf(fq[b * Kn + j], bk[j], acc);
  for (int m = 32; m; m >>= 1) acc += __shfl_xor(acc, m, 64);
  if (lane == 0) cb[b] = acc;
}

// ---------------- Wv fp32 [k][n] -> wvt bf16 [n][k] (LDS 64x64 transpose) --------
__global__ void k_twv(const float* __restrict__ wv, u16* __restrict__ wvt) {
  __shared__ u16 tile[64][72];
  int k0 = (blockIdx.x & 15) * 64, n0 = (blockIdx.x >> 4) * 64;
  int tid = threadIdx.x;
  int r = tid >> 2, c0 = (tid & 3) * 16;
#pragma unroll
  for (int i = 0; i < 4; ++i) {
    float4 vv = *reinterpret_cast<const float4*>(wv + (size_t)(k0 + r) * Kn + n0 + c0 + i * 4);
    tile[r][c0 + i * 4 + 0] = f2bf(vv.x);
    tile[r][c0 + i * 4 + 1] = f2bf(vv.y);
    tile[r][c0 + i * 4 + 2] = f2bf(vv.z);
    tile[r][c0 + i * 4 + 3] = f2bf(vv.w);
  }
  __syncthreads();
  int n = tid >> 2, kc = (tid & 3) * 16;
  alignas(16) u16 o[16];
#pragma unroll
  for (int i = 0; i < 16; ++i) o[i] = tile[kc + i][n];
  *reinterpret_cast<u16x8*>(wvt + (size_t)(n0 + n) * Kn + k0 + kc)     = *reinterpret_cast<u16x8*>(&o[0]);
  *reinterpret_cast<u16x8*>(wvt + (size_t)(n0 + n) * Kn + k0 + kc + 8) = *reinterpret_cast<u16x8*>(&o[8]);
}

// ---------------- v fp32 -> vb bf16 (row-major), HALF batch (4 b) ----------------
__global__ void k_tv(const float* __restrict__ v, u16* __restrict__ vb) {
  size_t t = (size_t)blockIdx.x * 256 + threadIdx.x;   // 2097152
  const float4* p = reinterpret_cast<const float4*>(v + t * 8);
  float4 a = p[0], b = p[1];
  u16x8 o = { f2bf(a.x), f2bf(a.y), f2bf(a.z), f2bf(a.w),
              f2bf(b.x), f2bf(b.y), f2bf(b.z), f2bf(b.w) };
  *reinterpret_cast<u16x8*>(vb + t * 8) = o;
}

// ---------------- attn = sigmoid((g.k_s + cb)/32), dual store ----------------
__global__ void k_attn(const float* __restrict__ kmat, const float* __restrict__ g,
                       const float* __restrict__ cb, float* __restrict__ out_attn,
                       float* __restrict__ attn_ws) {
  int row = blockIdx.x * 4 + (threadIdx.x >> 6);  // 32768
  int lane = threadIdx.x & 63;
  int b = row >> 12;
  const float4* kr = reinterpret_cast<const float4*>(kmat + (size_t)row * Dn);
  const float4* gr = reinterpret_cast<const float4*>(g + b * Dn);
  float acc = 0.f;
#pragma unroll
  for (int i = 0; i < 4; ++i) {
    float4 kv = kr[lane + 64 * i];
    float4 gv = gr[lane + 64 * i];
    acc = fmaf(kv.x, gv.x, acc); acc = fmaf(kv.y, gv.y, acc);
    acc = fmaf(kv.z, gv.z, acc); acc = fmaf(kv.w, gv.w, acc);
  }
  for (int m = 32; m; m >>= 1) acc += __shfl_xor(acc, m, 64);
  if (lane == 0) {
    float logit = (acc + cb[b]) * 0.03125f;
    float s = 1.f / (1.f + expf(-logit));
    out_attn[row] = s;
    attn_ws[row] = s;
  }
}

// ---------------- norm2 GEMM: m97 structure, BK=64, global_load_lds --------------
// HALF batch: grid 1024 = b(4) x nb(8) x sb(32). vb/norm2 pointers pre-offset.
// LDS layout: row r (128 B = 8 chunks of 16 B), chunk c stored at pos c^(r&7).
// Swizzle applied on the SOURCE side: lane i of stage-inst u fetches
// row u*8+(i>>3), chunk (i&7)^(i>>3); HW scatters to base+i*16.
__global__ __launch_bounds__(256)
void k_norm2(const u16* __restrict__ vb, const u16* __restrict__ wvt,
             const float* __restrict__ bv, float* __restrict__ norm2) {
  int blk = blockIdx.x;          // 1024: b(4) x nb(8) x sb(32), sb fastest
  int b  = blk >> 8;             // local b in [0,4)
  int nb = (blk >> 5) & 7;
  int sb = blk & 31;
  int s0 = sb * 128, n0 = nb * 128;

  __shared__ u16 As[128 * 64];
  __shared__ u16 Bs[128 * 64];
  __shared__ float nrm[128];

  int tid = threadIdx.x;
  int wave = tid >> 6, lane = tid & 63;
  int wr = wave & 1, wc = wave >> 1;
  int m = lane & 15, q = lane >> 4;

  f32x4 acc[4][4];
#pragma unroll
  for (int i = 0; i < 4; ++i)
#pragma unroll
    for (int j = 0; j < 4; ++j) acc[i][j] = (f32x4){0.f, 0.f, 0.f, 0.f};
  if (tid < 128) nrm[tid] = 0.f;

  int lrow = lane >> 3;                 // 0..7
  int lchunk = (lane & 7) ^ lrow;       // source chunk for this lane
  const u16* gA0 = vb  + ((size_t)(b * Sn + s0) + lrow) * 1024 + lchunk * 8;
  const u16* gB0 = wvt + ((size_t)(n0 + lrow)) * 1024 + lchunk * 8;

  for (int k0 = 0; k0 < 1024; k0 += 64) {
    __syncthreads();
#pragma unroll
    for (int t = 0; t < 4; ++t) {
      int u = wave * 4 + t;
      __builtin_amdgcn_global_load_lds(
          (const __attribute__((address_space(1))) void*)(gA0 + (size_t)u * 8 * 1024 + k0),
          (__attribute__((address_space(3))) void*)(&As[u * 512]), 16, 0, 0);
      __builtin_amdgcn_global_load_lds(
          (const __attribute__((address_space(1))) void*)(gB0 + (size_t)u * 8 * 1024 + k0),
          (__attribute__((address_space(3))) void*)(&Bs[u * 512]), 16, 0, 0);
    }
    __syncthreads();

    bf16x8 a[4][2], bf[4][2];
#pragma unroll
    for (int rt = 0; rt < 4; ++rt) {
      int r = wr * 64 + rt * 16 + m;
#pragma unroll
      for (int j = 0; j < 2; ++j) {
        int c = j * 4 + q;
        u16x8 raw = *reinterpret_cast<const u16x8*>(&As[r * 64 + ((c ^ (r & 7)) * 8)]);
        a[rt][j] = __builtin_bit_cast(bf16x8, raw);
      }
    }
#pragma unroll
    for (int ct = 0; ct < 4; ++ct) {
      int n = wc * 64 + ct * 16 + m;
#pragma unroll
      for (int j = 0; j < 2; ++j) {
        int c = j * 4 + q;
        u16x8 raw = *reinterpret_cast<const u16x8*>(&Bs[n * 64 + ((c ^ (n & 7)) * 8)]);
        bf[ct][j] = __builtin_bit_cast(bf16x8, raw);
      }
    }
#pragma unroll
    for (int j = 0; j < 2; ++j)
#pragma unroll
      for (int rt = 0; rt < 4; ++rt)
#pragma unroll
        for (int ct = 0; ct < 4; ++ct)
          acc[rt][ct] = __builtin_amdgcn_mfma_f32_16x16x32_bf16(a[rt][j], bf[ct][j],
                                                                acc[rt][ct], 0, 0, 0);
  }

  // epilogue: row-wise sum of squares (C/D: col=lane&15, row=q*4+reg)
  float bvv[4];
#pragma unroll
  for (int ct = 0; ct < 4; ++ct) bvv[ct] = bv[n0 + wc * 64 + ct * 16 + m];

#pragma unroll
  for (int rt = 0; rt < 4; ++rt) {
#pragma unroll
    for (int reg = 0; reg < 4; ++reg) {
      float ss = 0.f;
#pragma unroll
      for (int ct = 0; ct < 4; ++ct) {
        float f = acc[rt][ct][reg] + bvv[ct];
        ss = fmaf(f, f, ss);
      }
      ss += __shfl_xor(ss, 1, 64);
      ss += __shfl_xor(ss, 2, 64);
      ss += __shfl_xor(ss, 4, 64);
      ss += __shfl_xor(ss, 8, 64);
      if (m == 0) {
        int r = wr * 64 + rt * 16 + q * 4 + reg;
        atomicAdd(&nrm[r], ss);
      }
    }
  }
  __syncthreads();
  if (tid < 128) atomicAdd(&norm2[b * Sn + s0 + tid], nrm[tid]);
}

// ---------------- y[b,d] = sum_s coef_s vb[b,s,d]; csum (HALF batch) -------------
__global__ void k_wsum(const u16* __restrict__ vb, const float* __restrict__ attn,
                       const float* __restrict__ norm2, float* __restrict__ y,
                       float* __restrict__ csum) {
  int blk = blockIdx.x;         // 256: b(4) x sc(64 chunks of 64)
  int b = blk >> 6;             // local b in [0,4)
  int sc = (blk & 63) * 64;
  __shared__ float coef[64];
  int tid = threadIdx.x;
  if (tid < 64) {
    int s = sc + tid;
    coef[tid] = attn[b * Sn + s] / fmaxf(1.f, sqrtf(norm2[b * Sn + s]));
  }
  __syncthreads();
  if (tid == 0) {
    float cs = 0.f;
    for (int i = 0; i < 64; ++i) cs += coef[i];
    atomicAdd(&csum[b], cs);
  }
  const u16* vbb = vb + ((size_t)b * Sn + sc) * Dn;
  int d0 = tid * 4;
  float a0 = 0.f, a1 = 0.f, a2 = 0.f, a3 = 0.f;
  for (int i = 0; i < 64; ++i) {
    float c = coef[i];
    u16x4 r = *reinterpret_cast<const u16x4*>(vbb + (size_t)i * Dn + d0);
    a0 = fmaf(c, bf2f(r[0]), a0); a1 = fmaf(c, bf2f(r[1]), a1);
    a2 = fmaf(c, bf2f(r[2]), a2); a3 = fmaf(c, bf2f(r[3]), a3);
  }
  atomicAdd(&y[b * Dn + d0 + 0], a0);
  atomicAdd(&y[b * Dn + d0 + 1], a1);
  atomicAdd(&y[b * Dn + d0 + 2], a2);
  atomicAdd(&y[b * Dn + d0 + 3], a3);
}

// ---------------- seed = y@Wv + csum*bv + 0.1*noise, split-K ----------------
__global__ void k_seed(const float* __restrict__ y, const float* __restrict__ wv,
                       const float* __restrict__ bv, const float* __restrict__ csum,
                       float* __restrict__ out_seed) {
  int blk = blockIdx.x;               // b(8) x jc(4) x dc(8)
  int b = blk >> 5, jc = (blk >> 3) & 3, dc = blk & 7;
  int j = jc * 256 + threadIdx.x;
  const float* yb = y + b * Dn;
  float acc = 0.f;
  int d0 = dc * 128;
  for (int d = d0; d < d0 + 128; ++d)
    acc = fmaf(yb[d], wv[(size_t)d * Kn + j], acc);
  if (dc == 0) {
    acc += csum[b] * bv[j];
    int t = b * Kn + j;
    uint32_t o0, o1;
    threefry2x32(0u, 1234u, 0u, (uint32_t)t, &o0, &o1);
    uint32_t bits = o0 ^ o1;
    float f = __uint_as_float((bits >> 9) | 0x3F800000u) - 1.0f;
    float lo = __uint_as_float(0xBF7FFFFFu);
    float u = f * (1.0f - lo) + lo;
    u = fmaxf(u, lo);
    acc += 1.41421356237f * erfinv_f(u) * 0.1f;
  }
  atomicAdd(&out_seed[b * Kn + j], acc);
}

extern "C" void kernel_launch(void* const* d_in, const int* in_sizes, int n_in,
                              void* d_out, int out_size, void* d_ws, size_t ws_size,
                              hipStream_t stream) {
  const float* q  = (const float*)d_in[0];
  const float* k  = (const float*)d_in[1];
  const float* v  = (const float*)d_in[2];
  const float* wq = (const float*)d_in[3];
  const float* bq = (const float*)d_in[4];
  const float* wk = (const float*)d_in[5];
  const float* bk = (const float*)d_in[6];
  const float* wv = (const float*)d_in[7];
  const float* bv = (const float*)d_in[8];
  float* out = (float*)d_out;
  float* ws = (float*)d_ws;

  // ws floats: fq[0,8192) g[8192,16384) cb[16384,16392) csum[16392,16400)
  //            norm2[16896,49664) y[49664,57856) attn_ws[57856,90624)
  // bytes: wvt @ [393216, 393216+2MiB) ; vb @ [4MiB, 4MiB+32MiB) -> high-water 36MiB
  float* fq      = ws;
  float* g       = ws + 8192;
  float* cb      = ws + 16384;
  float* csum    = ws + 16392;
  float* norm2   = ws + 16896;
  float* y       = ws + 49664;
  float* attn_ws = ws + 57856;
  u16* wvt = (u16*)((char*)d_ws + 393216);
  u16* vb  = (u16*)((char*)d_ws + (4 << 20));

  hipMemsetAsync(ws, 0, 57856 * sizeof(float), stream);       // fq,g,cb,csum,norm2,y
  hipMemsetAsync(out, 0, 8192 * sizeof(float), stream);       // seed accum base
  k_fq  <<<256,   256, 0, stream>>>(q, wq, bq, fq);
  k_g   <<<2048,  256, 0, stream>>>(wk, fq, g);
  k_cb  <<<1,     512, 0, stream>>>(fq, bk, cb);
  k_twv <<<256,   256, 0, stream>>>(wv, wvt);
  k_attn<<<8192,  256, 0, stream>>>(k, g, cb, out + 8192, attn_ws);
  for (int h = 0; h < 2; ++h) {
    const float* vh = v + (size_t)h * 4 * Sn * Dn;
    k_tv   <<<8192, 256, 0, stream>>>(vh, vb);
    k_norm2<<<1024, 256, 0, stream>>>(vb, wvt, bv, norm2 + (size_t)h * 4 * Sn);
    k_wsum <<<256,  256, 0, stream>>>(vb, attn_ws + (size_t)h * 4 * Sn,
                                      norm2 + (size_t)h * 4 * Sn,
                                      y + (size_t)h * 4 * Dn, csum + h * 4);
  }
  k_seed<<<256,   256, 0, stream>>>(y, wv, bv, csum, out);
}

// Round 3
// 433.472 us; speedup vs baseline: 1.0295x; 1.0295x over previous
//
#include <hip/hip_runtime.h>
#include <stdint.h>

// DP_Attention: B=8, S=4096, D=K=1024, fp32.
// Fused structure (6 dispatches):
//   memset(fq, seed_acc)
//   k_prep : blocks 0-255 fq = q@Wq+bq (split-K atomic); 256-511 wvt = bf16(Wv^T)
//   k_gcb  : blocks 0-2047 g[b]=Wk@fq[b]; 2048-2055 cb[b]=fq[b].bk
//   k_attn : attn = sigmoid((g.k_s+cb)/32)  -> d_out[8192:] and attn_ws
//   k_fv   : per block: 64 fv rows x FULL N=1024. A-tile (v, fp32->bf16) in 8KB
//            swizzled LDS, reused by 8 waves; B (wvt, 2MB, L2-resident) read
//            directly from global per-fragment. Row norm in-block ->
//            coef = attn/max(1,||fv||) -> atomicAdd sum_s coef*(fv+bv) into seed_acc.
//   k_final: out = seed_acc + 0.1*noise (threefry, partitioned)
// NOTE: no dynamic LDS, no hipFuncSetAttribute (round-2 container failure suspect).

#define Bn 8
#define Sn 4096
#define Dn 1024
#define Kn 1024

typedef unsigned short u16;
typedef __attribute__((ext_vector_type(8))) unsigned short u16x8;
typedef __attribute__((ext_vector_type(8))) __bf16 bf16x8;
typedef __attribute__((ext_vector_type(4))) float f32x4;

__device__ __forceinline__ u16 f2bf(float f) {
  uint32_t x = __float_as_uint(f);
  x += 0x7FFFu + ((x >> 16) & 1u);   // RNE
  return (u16)(x >> 16);
}

// ---------------- JAX threefry2x32 (key=(0,1234)), partitionable ----------------
__device__ __forceinline__ uint32_t rotl32(uint32_t x, int d) {
  return (x << d) | (x >> (32 - d));
}
__device__ void threefry2x32(uint32_t k0, uint32_t k1, uint32_t x0, uint32_t x1,
                             uint32_t* o0, uint32_t* o1) {
  uint32_t ks0 = k0, ks1 = k1, ks2 = k0 ^ k1 ^ 0x1BD11BDAu;
  x0 += ks0; x1 += ks1;
#define TF_R4(a,b,c,d) \
  x0 += x1; x1 = rotl32(x1,a); x1 ^= x0; \
  x0 += x1; x1 = rotl32(x1,b); x1 ^= x0; \
  x0 += x1; x1 = rotl32(x1,c); x1 ^= x0; \
  x0 += x1; x1 = rotl32(x1,d); x1 ^= x0;
  TF_R4(13,15,26,6);  x0 += ks1; x1 += ks2 + 1u;
  TF_R4(17,29,16,24); x0 += ks2; x1 += ks0 + 2u;
  TF_R4(13,15,26,6);  x0 += ks0; x1 += ks1 + 3u;
  TF_R4(17,29,16,24); x0 += ks1; x1 += ks2 + 4u;
  TF_R4(13,15,26,6);  x0 += ks2; x1 += ks0 + 5u;
#undef TF_R4
  *o0 = x0; *o1 = x1;
}

__device__ float erfinv_f(float x) {
  float w = -log1pf(-x * x);
  float p;
  if (w < 5.0f) {
    w -= 2.5f;
    p = 2.81022636e-08f;
    p = fmaf(p, w, 3.43273939e-07f);
    p = fmaf(p, w, -3.5233877e-06f);
    p = fmaf(p, w, -4.39150654e-06f);
    p = fmaf(p, w, 0.00021858087f);
    p = fmaf(p, w, -0.00125372503f);
    p = fmaf(p, w, -0.00417768164f);
    p = fmaf(p, w, 0.246640727f);
    p = fmaf(p, w, 1.50140941f);
  } else {
    w = sqrtf(w) - 3.0f;
    p = -0.000200214257f;
    p = fmaf(p, w, 0.000100950558f);
    p = fmaf(p, w, 0.00134934322f);
    p = fmaf(p, w, -0.00367342844f);
    p = fmaf(p, w, 0.00573950773f);
    p = fmaf(p, w, -0.0076224613f);
    p = fmaf(p, w, 0.00943887047f);
    p = fmaf(p, w, 1.00167406f);
    p = fmaf(p, w, 2.83297682f);
  }
  return p * x;
}

// ---------------- k_prep: fq (blocks 0-255) + Wv transpose (blocks 256-511) -----
__global__ void k_prep(const float* __restrict__ q, const float* __restrict__ wq,
                       const float* __restrict__ bq, float* __restrict__ fq,
                       const float* __restrict__ wv, u16* __restrict__ wvt) {
  __shared__ u16 tile[64][72];
  int tid = threadIdx.x;
  if (blockIdx.x < 256) {
    int blk = blockIdx.x;               // b(8) x jc(4) x dc(8)
    int b = blk >> 5, jc = (blk >> 3) & 3, dc = blk & 7;
    int j = jc * 256 + tid;
    const float* qb = q + b * Dn;
    float acc = 0.f;
    int d0 = dc * 128;
    for (int d = d0; d < d0 + 128; ++d)
      acc = fmaf(qb[d], wq[(size_t)d * Kn + j], acc);
    if (dc == 0) acc += bq[j];
    atomicAdd(&fq[b * Kn + j], acc);
  } else {
    int idx = blockIdx.x - 256;
    int k0 = (idx & 15) * 64, n0 = (idx >> 4) * 64;
    int r = tid >> 2, c0 = (tid & 3) * 16;
#pragma unroll
    for (int i = 0; i < 4; ++i) {
      float4 vv = *reinterpret_cast<const float4*>(wv + (size_t)(k0 + r) * Kn + n0 + c0 + i * 4);
      tile[r][c0 + i * 4 + 0] = f2bf(vv.x);
      tile[r][c0 + i * 4 + 1] = f2bf(vv.y);
      tile[r][c0 + i * 4 + 2] = f2bf(vv.z);
      tile[r][c0 + i * 4 + 3] = f2bf(vv.w);
    }
    __syncthreads();
    int n = tid >> 2, kc = (tid & 3) * 16;
    alignas(16) u16 o[16];
#pragma unroll
    for (int i = 0; i < 16; ++i) o[i] = tile[kc + i][n];
    *reinterpret_cast<u16x8*>(wvt + (size_t)(n0 + n) * Kn + k0 + kc)     = *reinterpret_cast<u16x8*>(&o[0]);
    *reinterpret_cast<u16x8*>(wvt + (size_t)(n0 + n) * Kn + k0 + kc + 8) = *reinterpret_cast<u16x8*>(&o[8]);
  }
}

// ---------------- k_gcb: g (blocks 0-2047) + cb (blocks 2048-2055) ----------------
__global__ void k_gcb(const float* __restrict__ wk, const float* __restrict__ fq,
                      const float* __restrict__ bk, float* __restrict__ g,
                      float* __restrict__ cb) {
  int tid = threadIdx.x;
  if (blockIdx.x < 2048) {
    int wid = (blockIdx.x * 256 + tid) >> 6;   // 8192 waves
    int lane = tid & 63;
    int b = wid >> 10, d = wid & 1023;
    const float* row = wk + (size_t)d * Kn;
    const float* f = fq + b * Kn;
    float acc = 0.f;
    for (int j = lane; j < Kn; j += 64) acc = fmaf(row[j], f[j], acc);
    for (int m = 32; m; m >>= 1) acc += __shfl_xor(acc, m, 64);
    if (lane == 0) g[b * Dn + d] = acc;
  } else if (tid < 64) {
    int b = blockIdx.x - 2048;
    float acc = 0.f;
    for (int j = tid; j < Kn; j += 64) acc = fmaf(fq[b * Kn + j], bk[j], acc);
    for (int m = 32; m; m >>= 1) acc += __shfl_xor(acc, m, 64);
    if (tid == 0) cb[b] = acc;
  }
}

// ---------------- attn = sigmoid((g.k_s + cb)/32), dual store ----------------
__global__ void k_attn(const float* __restrict__ kmat, const float* __restrict__ g,
                       const float* __restrict__ cb, float* __restrict__ out_attn,
                       float* __restrict__ attn_ws) {
  int row = blockIdx.x * 4 + (threadIdx.x >> 6);  // 32768
  int lane = threadIdx.x & 63;
  int b = row >> 12;
  const float4* kr = reinterpret_cast<const float4*>(kmat + (size_t)row * Dn);
  const float4* gr = reinterpret_cast<const float4*>(g + b * Dn);
  float acc = 0.f;
#pragma unroll
  for (int i = 0; i < 4; ++i) {
    float4 kv = kr[lane + 64 * i];
    float4 gv = gr[lane + 64 * i];
    acc = fmaf(kv.x, gv.x, acc); acc = fmaf(kv.y, gv.y, acc);
    acc = fmaf(kv.z, gv.z, acc); acc = fmaf(kv.w, gv.w, acc);
  }
  for (int m = 32; m; m >>= 1) acc += __shfl_xor(acc, m, 64);
  if (lane == 0) {
    float logit = (acc + cb[b]) * 0.03125f;
    float s = 1.f / (1.f + expf(-logit));
    out_attn[row] = s;
    attn_ws[row] = s;
  }
}

// ---------------- k_fv: fused fv GEMM + norm/clip + weighted seed reduce ---------
// Block: 64 rows (one b) x full N=1024. 512 thr (8 waves; wave w owns cols
// [w*128,(w+1)*128)). LDS: As[64][64] bf16 XOR-swizzled (8KB). B read directly
// from wvt (2MB, L2-resident): lane fragment = wvt[n][k0+c*8 ..+8), 16B loads.
// Swizzle: row r (128B = 8 chunks of 16B), chunk c stored at pos c^(r&7).
__global__ __launch_bounds__(512, 2)
void k_fv(const float* __restrict__ v, const u16* __restrict__ wvt,
          const float* __restrict__ bv, const float* __restrict__ attn,
          float* __restrict__ seed_acc) {
  __shared__ u16 As[64 * 64];      // 8 KiB
  __shared__ float nrm[64];
  __shared__ float coef[64];

  int r0 = blockIdx.x * 64;
  int b  = r0 >> 12;
  int s0 = r0 & (Sn - 1);

  int tid = threadIdx.x;
  int wave = tid >> 6, lane = tid & 63;
  int m = lane & 15, qq = lane >> 4;

  if (tid < 64) nrm[tid] = 0.f;

  f32x4 acc[4][8];
#pragma unroll
  for (int i = 0; i < 4; ++i)
#pragma unroll
    for (int j = 0; j < 8; ++j) acc[i][j] = (f32x4){0.f, 0.f, 0.f, 0.f};

  // A staging: thread covers row tid>>3, chunk tid&7 (fp32 -> bf16, swizzled write)
  int arow = tid >> 3, achunk = tid & 7;
  const float* gA0 = v + ((size_t)(b * Sn + s0) + arow) * Dn + achunk * 8;
  int apos = (achunk ^ (arow & 7)) * 8;   // u16 offset within row

  // B base per lane: rows wave*128 + ct*16 + m of wvt
  const u16* gB = wvt + (size_t)(wave * 128 + m) * Kn;

  // prefetch first A chunk
  float4 pa0 = reinterpret_cast<const float4*>(gA0)[0];
  float4 pa1 = reinterpret_cast<const float4*>(gA0)[1];

  for (int k0 = 0; k0 < 1024; k0 += 64) {
    __syncthreads();
    {
      u16x8 o = { f2bf(pa0.x), f2bf(pa0.y), f2bf(pa0.z), f2bf(pa0.w),
                  f2bf(pa1.x), f2bf(pa1.y), f2bf(pa1.z), f2bf(pa1.w) };
      *reinterpret_cast<u16x8*>(&As[arow * 64 + apos]) = o;
    }
    if (k0 < 960) {   // issue next A load; overlaps with MFMA below
      const float4* pa = reinterpret_cast<const float4*>(gA0 + k0 + 64);
      pa0 = pa[0]; pa1 = pa[1];
    }
    __syncthreads();

#pragma unroll
    for (int j = 0; j < 2; ++j) {
      int c = j * 4 + qq;
      bf16x8 a[4];
#pragma unroll
      for (int rt = 0; rt < 4; ++rt) {
        int r = rt * 16 + m;
        u16x8 raw = *reinterpret_cast<const u16x8*>(&As[r * 64 + ((c ^ (r & 7)) * 8)]);
        a[rt] = __builtin_bit_cast(bf16x8, raw);
      }
#pragma unroll
      for (int ct = 0; ct < 8; ++ct) {
        u16x8 raw = *reinterpret_cast<const u16x8*>(gB + (size_t)ct * 16 * Kn + k0 + c * 8);
        bf16x8 bb = __builtin_bit_cast(bf16x8, raw);
#pragma unroll
        for (int rt = 0; rt < 4; ++rt)
          acc[rt][ct] = __builtin_amdgcn_mfma_f32_16x16x32_bf16(a[rt], bb, acc[rt][ct], 0, 0, 0);
      }
    }
  }

  // bias per owned col (C/D layout: col = lane&15, row = qq*4+reg)
  float bvv[8];
#pragma unroll
  for (int ct = 0; ct < 8; ++ct) bvv[ct] = bv[wave * 128 + ct * 16 + m];

  // row sum-of-squares: per (rt,reg) sum this lane's 8 cols, reduce over m
#pragma unroll
  for (int rt = 0; rt < 4; ++rt) {
#pragma unroll
    for (int reg = 0; reg < 4; ++reg) {
      float ss = 0.f;
#pragma unroll
      for (int ct = 0; ct < 8; ++ct) {
        float f = acc[rt][ct][reg] + bvv[ct];
        ss = fmaf(f, f, ss);
      }
      ss += __shfl_xor(ss, 1, 64);
      ss += __shfl_xor(ss, 2, 64);
      ss += __shfl_xor(ss, 4, 64);
      ss += __shfl_xor(ss, 8, 64);
      if (m == 0) atomicAdd(&nrm[rt * 16 + qq * 4 + reg], ss);
    }
  }
  __syncthreads();
  if (tid < 64)
    coef[tid] = attn[b * Sn + s0 + tid] / fmaxf(1.f, sqrtf(nrm[tid]));
  __syncthreads();

  // weighted reduce over rows: seed[b, col] += sum_rows coef[row]*(fv+bv)
#pragma unroll
  for (int ct = 0; ct < 8; ++ct) {
    float t = 0.f;
#pragma unroll
    for (int rt = 0; rt < 4; ++rt) {
#pragma unroll
      for (int reg = 0; reg < 4; ++reg) {
        float cf = coef[rt * 16 + qq * 4 + reg];
        t = fmaf(cf, acc[rt][ct][reg] + bvv[ct], t);
      }
    }
    t += __shfl_xor(t, 16, 64);
    t += __shfl_xor(t, 32, 64);
    if (qq == 0) atomicAdd(&seed_acc[b * Kn + wave * 128 + ct * 16 + m], t);
  }
}

// ---------------- k_final: out = seed_acc + 0.1*noise ----------------
__global__ void k_final(const float* __restrict__ seed_acc, float* __restrict__ out) {
  int t = blockIdx.x * 256 + threadIdx.x;   // 8192
  uint32_t o0, o1;
  threefry2x32(0u, 1234u, 0u, (uint32_t)t, &o0, &o1);
  uint32_t bits = o0 ^ o1;
  float f = __uint_as_float((bits >> 9) | 0x3F800000u) - 1.0f;
  float lo = __uint_as_float(0xBF7FFFFFu);
  float u = f * (1.0f - lo) + lo;
  u = fmaxf(u, lo);
  out[t] = seed_acc[t] + 1.41421356237f * erfinv_f(u) * 0.1f;
}

extern "C" void kernel_launch(void* const* d_in, const int* in_sizes, int n_in,
                              void* d_out, int out_size, void* d_ws, size_t ws_size,
                              hipStream_t stream) {
  const float* q  = (const float*)d_in[0];
  const float* k  = (const float*)d_in[1];
  const float* v  = (const float*)d_in[2];
  const float* wq = (const float*)d_in[3];
  const float* bq = (const float*)d_in[4];
  const float* wk = (const float*)d_in[5];
  const float* bk = (const float*)d_in[6];
  const float* wv = (const float*)d_in[7];
  const float* bv = (const float*)d_in[8];
  float* out = (float*)d_out;
  float* ws = (float*)d_ws;

  // ws floats: fq[0,8192) seed_acc[8192,16384) g[16384,24576) cb[24576,24584)
  //            attn_ws[24832,57600) ; wvt bytes @ [262144, 262144+2MiB)
  float* fq       = ws;
  float* seed_acc = ws + 8192;
  float* g        = ws + 16384;
  float* cb       = ws + 24576;
  float* attn_ws  = ws + 24832;
  u16* wvt = (u16*)((char*)d_ws + 262144);

  hipMemsetAsync(ws, 0, 16384 * sizeof(float), stream);       // fq + seed_acc
  k_prep <<<512,  256, 0, stream>>>(q, wq, bq, fq, wv, wvt);
  k_gcb  <<<2056, 256, 0, stream>>>(wk, fq, bk, g, cb);
  k_attn <<<8192, 256, 0, stream>>>(k, g, cb, out + 8192, attn_ws);
  k_fv   <<<512,  512, 0, stream>>>(v, wvt, bv, attn_ws, seed_acc);
  k_final<<<32,   256, 0, stream>>>(seed_acc, out);
}